// Round 13
// baseline (174.721 us; speedup 1.0000x reference)
//
#include <hip/hip_runtime.h>
#include <cstdint>
#include <cmath>

#define NROWS 8192
#define KDIM  512            // elements; also bytes/row in fp8

typedef int    i32x4  __attribute__((ext_vector_type(4)));
typedef int    i32x8  __attribute__((ext_vector_type(8)));
typedef float  f32x16 __attribute__((ext_vector_type(16)));
typedef unsigned char u8;

#define AS1(p) ((const __attribute__((address_space(1))) void*)(p))
#define AS3(p) ((__attribute__((address_space(3))) void*)(p))

// --- Kernel 1: row L2-normalize fp32 -> fp8 e4m3 (OCP, HW cvt), one wave/row.
// zi rows [0,8192), zj rows [8192,16384). Also zeroes the 128 accumulator slots.
__global__ __launch_bounds__(256) void nrm_kernel(const float* __restrict__ zi,
                                                  const float* __restrict__ zj,
                                                  u8* __restrict__ out,
                                                  double* __restrict__ acc) {
    if (blockIdx.x == 0 && threadIdx.x < 128) acc[threadIdx.x] = 0.0;
    const int wave = threadIdx.x >> 6;
    const int lane = threadIdx.x & 63;
    const int row  = blockIdx.x * 4 + wave;            // 0..16383
    const float* src = (row < NROWS) ? zi + (size_t)row * KDIM
                                     : zj + (size_t)(row - NROWS) * KDIM;
    float4 a = ((const float4*)src)[lane];
    float4 b = ((const float4*)src)[lane + 64];
    float ss = a.x*a.x + a.y*a.y + a.z*a.z + a.w*a.w
             + b.x*b.x + b.y*b.y + b.z*b.z + b.w*b.w;
    #pragma unroll
    for (int off = 32; off >= 1; off >>= 1) ss += __shfl_xor(ss, off, 64);
    const float inv = 1.0f / fmaxf(sqrtf(ss), 1e-12f);
    int p0 = 0, p1 = 0;
    p0 = __builtin_amdgcn_cvt_pk_fp8_f32(a.x * inv, a.y * inv, p0, false);
    p0 = __builtin_amdgcn_cvt_pk_fp8_f32(a.z * inv, a.w * inv, p0, true);
    p1 = __builtin_amdgcn_cvt_pk_fp8_f32(b.x * inv, b.y * inv, p1, false);
    p1 = __builtin_amdgcn_cvt_pk_fp8_f32(b.z * inv, b.w * inv, p1, true);
    int* dst = (int*)(out + (size_t)row * KDIM);
    dst[lane]      = p0;
    dst[lane + 64] = p1;
}

// --- Kernel 2: fused MX-fp8 A*B^T -> exp(10*dot) -> global sum.
// R12 structure: WAVE-INDEPENDENT 64x64 tiles, wave-private double-buffered LDS
// (2 x 8 KB per wave; 64 KB / 4-wave block -> 2 blocks/CU = 2 waves/SIMD), and
// ZERO __syncthreads anywhere. The barrier-coupled family (R2/R9/R10/R11)
// plateaued at ~85 µs with MFMA 26% / LDS 46%: the stall is 8-wave convergence
// + forced drain every k-iter. Here stage(k)->read(k) ordering is a PER-WAVE
// s_waitcnt vmcnt(0) (mechanism validated in R8; R8's regression was its
// 1 wave/SIMD occupancy, fixed here). K-iter: wait vmcnt(0) -> 8 ds_read_b128
// (buf cur) -> issue 8 global_load_lds for k+1 (buf nxt) -> 4 MFMAs. A/B bands
// are staged twice per block (wave-private copies) — LDS-DMA cost doubles but
// total LDS demand/block stays ~R9-level, with no convergence dead time.
// LDS XOR-swizzle (verified R2-R11, absmax 0): region = 32 rows x 64 B; chunk
// (r,b) at p = r*4 + (b ^ ((r>>1)&3)); staging inverse b = (lane&3)^((lane>>3)&3).
// Triangle bookkeeping per 64x64 tile (pos = zi*zi^T symmetric): skip nt<mt;
// nt>mt weight 2; nt==mt per-element rr==cc skip. Diagonal added in finalize.
__global__ __launch_bounds__(256, 2) void gemm_exp_reduce(const u8* __restrict__ A,
                                                          const u8* __restrict__ B,
                                                          double* __restrict__ acc) {
    const int tid  = threadIdx.x;
    const int lane = tid & 63;
    const int wave = tid >> 6;
    const int mt   = blockIdx.y * 2 + (wave >> 1);   // 64-row m-tile, 0..127
    const int nt   = blockIdx.x * 2 + (wave & 1);    // 64-row n-tile, 0..255
    const bool pos = (nt < 128);
    if (pos && nt < mt) return;     // strict lower-tri pos tile: mirror elsewhere
                                    // (no barriers in kernel -> per-wave return safe)

    __shared__ u8 lds[4][2][8192];  // [wave][buf][A 4KB (2 regions) | B 4KB]
    u8* myl = &lds[wave][0][0];

    f32x16 accf[2][2];
    #pragma unroll
    for (int i = 0; i < 2; ++i)
        #pragma unroll
        for (int j = 0; j < 2; ++j)
            #pragma unroll
            for (int r = 0; r < 16; ++r)
                accf[i][j][r] = 0.f;

    // staging (layout verified R2-R11): 16-row chunks of 1024 B; lane stages 16 B
    // at chunk*1024 + lane*16; global row = tile*64 + chunk*16 + (lane>>2),
    // 16B-col bsw = (lane&3)^((lane>>3)&3).
    const int bsw = (lane & 3) ^ ((lane >> 3) & 3);
    const u8* gA0 = A + (size_t)(mt * 64 + (lane >> 2)) * KDIM + bsw * 16;
    const u8* gB0 = B + (size_t)(nt * 64 + (lane >> 2)) * KDIM + bsw * 16;
    const int lo16 = lane * 16;

    // fragment read: lane row r=lane&31, k-half q=lane>>5 (16B chunks 2q,2q+1);
    // swizzled position p = r*4 + ((2q) ^ ((r>>1)&3)); partner chunk at ^16.
    const int r_  = lane & 31;
    const int q_  = lane >> 5;
    const int p16 = (r_ * 4 + ((2 * q_) ^ ((r_ >> 1) & 3))) * 16;

    // prologue: stage k-block 0 into buf 0 (4 A-chunks + 4 B-chunks)
    #pragma unroll
    for (int c = 0; c < 4; ++c) {
        __builtin_amdgcn_global_load_lds(AS1(gA0 + (size_t)c * 16 * KDIM),
                                         AS3(myl + c * 1024 + lo16), 16, 0, 0);
        __builtin_amdgcn_global_load_lds(AS1(gB0 + (size_t)c * 16 * KDIM),
                                         AS3(myl + 4096 + c * 1024 + lo16), 16, 0, 0);
    }

    #pragma unroll
    for (int kk = 0; kk < 8; ++kk) {
        const int cur = (kk & 1) * 8192;
        // drain this wave's own stage(kk) — per-wave vmcnt, no cross-wave coupling
        __builtin_amdgcn_s_waitcnt(0x0F70);   // vmcnt(0); lgkm/exp unconstrained

        i32x8 af[2], bfr[2];
        #pragma unroll
        for (int mi = 0; mi < 2; ++mi) {
            const int off = cur + mi * 2048 + p16;
            *(i32x4*)&af[mi]       = *(const i32x4*)&myl[off];
            *((i32x4*)&af[mi] + 1) = *(const i32x4*)&myl[off ^ 16];
        }
        #pragma unroll
        for (int ni = 0; ni < 2; ++ni) {
            const int off = cur + 4096 + ni * 2048 + p16;
            *(i32x4*)&bfr[ni]       = *(const i32x4*)&myl[off];
            *((i32x4*)&bfr[ni] + 1) = *(const i32x4*)&myl[off ^ 16];
        }

        if (kk < 7) {   // prefetch stage(kk+1) into the other buffer
            const int nxt = ((kk + 1) & 1) * 8192;
            const size_t kb = (size_t)(kk + 1) * 64;
            #pragma unroll
            for (int c = 0; c < 4; ++c) {
                __builtin_amdgcn_global_load_lds(AS1(gA0 + kb + (size_t)c * 16 * KDIM),
                                                 AS3(myl + nxt + c * 1024 + lo16), 16, 0, 0);
                __builtin_amdgcn_global_load_lds(AS1(gB0 + kb + (size_t)c * 16 * KDIM),
                                                 AS3(myl + nxt + 4096 + c * 1024 + lo16), 16, 0, 0);
            }
        }

        #pragma unroll
        for (int mi = 0; mi < 2; ++mi)
            #pragma unroll
            for (int ni = 0; ni < 2; ++ni)
                accf[mi][ni] = __builtin_amdgcn_mfma_scale_f32_32x32x64_f8f6f4(
                    af[mi], bfr[ni], accf[mi][ni],
                    0, 0,                 // cbsz=fp8(e4m3), blgp=fp8(e4m3)
                    0, 0x7f7f7f7f,        // scale_a: every byte = 2^0
                    0, 0x7f7f7f7f);       // scale_b
    }

    // epilogue: exp(10*d) = exp2(d*10/ln2); diag tile (nt==mt) skips rr==cc
    const float LOG2E10 = 14.4269504088896341f;
    float part = 0.f;
    if (pos && nt == mt) {
        #pragma unroll
        for (int mi = 0; mi < 2; ++mi)
            #pragma unroll
            for (int ni = 0; ni < 2; ++ni)
                #pragma unroll
                for (int r = 0; r < 16; ++r) {
                    // C/D 32x32: col=lane&31, row=(r&3)+8*(r>>2)+4*(lane>>5)
                    int rr = mi * 32 + ((r & 3) + 8 * (r >> 2) + 4 * q_);
                    int cc = ni * 32 + r_;
                    if (rr != cc) part += exp2f(accf[mi][ni][r] * LOG2E10);
                }
    } else {
        #pragma unroll
        for (int mi = 0; mi < 2; ++mi)
            #pragma unroll
            for (int ni = 0; ni < 2; ++ni)
                #pragma unroll
                for (int r = 0; r < 16; ++r)
                    part += exp2f(accf[mi][ni][r] * LOG2E10);
    }

    #pragma unroll
    for (int off = 32; off >= 1; off >>= 1) part += __shfl_xor(part, off, 64);
    if (lane == 0) {
        double s = (double)part;
        if (pos && nt > mt) s *= 2.0;    // stands in for its skipped mirror
        atomicAdd(&acc[(pos ? 0 : 64) + (((unsigned)nt * 7 + (unsigned)mt) & 63)], s);
    }
}

// --- Kernel 3: loss = log1p(neg/pos), pos += exact diagonal 8192*e^10.
// 128 threads, one global load each; LDS reduce then scalar finish.
__global__ __launch_bounds__(128) void finalize(const double* __restrict__ acc,
                                                float* __restrict__ out) {
    __shared__ double sp[128];
    const int t = threadIdx.x;
    sp[t] = acc[t];
    __syncthreads();
    if (t == 0) {
        double p = 0.0, n = 0.0;
        #pragma unroll
        for (int i = 0; i < 64; ++i) { p += sp[i]; n += sp[64 + i]; }
        p += 8192.0 * exp(10.0);
        out[0] = (float)log1p(n / p);
    }
}

extern "C" void kernel_launch(void* const* d_in, const int* in_sizes, int n_in,
                              void* d_out, int out_size, void* d_ws, size_t ws_size,
                              hipStream_t stream) {
    const float* zi = (const float*)d_in[0];
    const float* zj = (const float*)d_in[1];
    u8* nrm = (u8*)d_ws;                                      // [16384][512] fp8 = 8 MB
    double* acc = (double*)((char*)d_ws + (size_t)16384 * 512);

    nrm_kernel<<<4096, 256, 0, stream>>>(zi, zj, nrm, acc);
    dim3 grid(128, 64);   // x: 256 n-tiles / 2 per block, y: 128 m-tiles / 2 per block
    gemm_exp_reduce<<<grid, 256, 0, stream>>>(nrm, nrm, acc);
    finalize<<<1, 128, 0, stream>>>(acc, (float*)d_out);
}